// Round 1
// baseline (293.147 us; speedup 1.0000x reference)
//
#include <hip/hip_runtime.h>
#include <math.h>

#define DM    1024
#define DS    16
#define DTR   64
#define NP    96            // DTR + 2*DS
#define BB    4
#define LSEQ  2048
#define NROWS (BB*LSEQ)     // 8192
#define NCHUNK 32
#define LC    (LSEQ/NCHUNK) // 64

// ---------------------------------------------------------------------------
// K1: proj[8192][96] = x[8192][1024] * Wx[96][1024]^T   (split-K + atomics)
// ---------------------------------------------------------------------------
#define K1_BM 64
#define K1_KSPLIT 4
#define K1_KRANGE (DM / K1_KSPLIT)

__global__ __launch_bounds__(256) void k1_proj(const float* __restrict__ x,
                                               const float* __restrict__ Wx,
                                               float* __restrict__ proj) {
  __shared__ float Xs[K1_BM][68];   // [m][k], stride 68 (16B-aligned rows, 2-way banks max)
  __shared__ float Ws[NP][69];      // [p][k], stride 69 (odd -> conflict-free col reads)
  const int tid = threadIdx.x;
  const int r0 = blockIdx.x * K1_BM;
  const int kbase = blockIdx.y * K1_KRANGE;
  const int tn = tid & 15, tm = tid >> 4;
  const int kq = tid & 15, mr = tid >> 4;

  float acc[4][6];
#pragma unroll
  for (int i = 0; i < 4; ++i)
#pragma unroll
    for (int j = 0; j < 6; ++j) acc[i][j] = 0.f;

  for (int ch = 0; ch < K1_KRANGE / 64; ++ch) {
    const int kb = kbase + ch * 64;
    // stage X tile: 64 rows x 64 k (coalesced 256B runs per row)
#pragma unroll
    for (int ii = 0; ii < 4; ++ii) {
      const int m = mr + ii * 16;
      float4 v = *(const float4*)(x + (r0 + m) * DM + kb + kq * 4);
      *(float4*)&Xs[m][kq * 4] = v;
    }
    // stage W tile: 96 rows x 64 k
#pragma unroll
    for (int ii = 0; ii < 6; ++ii) {
      const int idx = tid + ii * 256;
      const int p = idx >> 4, kq2 = idx & 15;
      float4 v = *(const float4*)(Wx + p * DM + kb + kq2 * 4);
      Ws[p][kq2 * 4 + 0] = v.x; Ws[p][kq2 * 4 + 1] = v.y;
      Ws[p][kq2 * 4 + 2] = v.z; Ws[p][kq2 * 4 + 3] = v.w;
    }
    __syncthreads();
#pragma unroll 4
    for (int kk = 0; kk < 64; ++kk) {
      float a[4], w[6];
#pragma unroll
      for (int i = 0; i < 4; ++i) a[i] = Xs[tm * 4 + i][kk];
#pragma unroll
      for (int j = 0; j < 6; ++j) w[j] = Ws[tn * 6 + j][kk];
#pragma unroll
      for (int i = 0; i < 4; ++i)
#pragma unroll
        for (int j = 0; j < 6; ++j) acc[i][j] = fmaf(a[i], w[j], acc[i][j]);
    }
    __syncthreads();
  }
#pragma unroll
  for (int i = 0; i < 4; ++i)
#pragma unroll
    for (int j = 0; j < 6; ++j)
      atomicAdd(&proj[(r0 + tm * 4 + i) * NP + tn * 6 + j], acc[i][j]);
}

// ---------------------------------------------------------------------------
// K2: dt[8192][1024] = softplus(dt_r[8192][64] * dt_W[1024][64]^T + dt_b)
//     written into d_out (later overwritten in-place by y in phase C)
// ---------------------------------------------------------------------------
__global__ __launch_bounds__(256) void k2_dt(const float* __restrict__ proj,
                                             const float* __restrict__ dt_W,
                                             const float* __restrict__ dt_b,
                                             float* __restrict__ dtb) {
  __shared__ float Xs[64][68];
  __shared__ float Ws[64][69];
  const int tid = threadIdx.x;
  const int r0 = blockIdx.x * 64;
  const int n0 = blockIdx.y * 64;
  const int kq = tid & 15, mr = tid >> 4;
#pragma unroll
  for (int ii = 0; ii < 4; ++ii) {
    const int m = mr + ii * 16;
    float4 v = *(const float4*)(proj + (r0 + m) * NP + kq * 4);  // dt_r slice (cols 0..63)
    *(float4*)&Xs[m][kq * 4] = v;
    float4 w = *(const float4*)(dt_W + (n0 + m) * DTR + kq * 4);
    Ws[m][kq * 4 + 0] = w.x; Ws[m][kq * 4 + 1] = w.y;
    Ws[m][kq * 4 + 2] = w.z; Ws[m][kq * 4 + 3] = w.w;
  }
  __syncthreads();
  const int tn = tid & 15, tm = tid >> 4;
  float acc[4][4];
#pragma unroll
  for (int i = 0; i < 4; ++i)
#pragma unroll
    for (int j = 0; j < 4; ++j) acc[i][j] = 0.f;
#pragma unroll 4
  for (int kk = 0; kk < DTR; ++kk) {
    float a[4], w[4];
#pragma unroll
    for (int i = 0; i < 4; ++i) a[i] = Xs[tm * 4 + i][kk];
#pragma unroll
    for (int j = 0; j < 4; ++j) w[j] = Ws[tn * 4 + j][kk];
#pragma unroll
    for (int i = 0; i < 4; ++i)
#pragma unroll
      for (int j = 0; j < 4; ++j) acc[i][j] = fmaf(a[i], w[j], acc[i][j]);
  }
  float4 bb = *(const float4*)(dt_b + n0 + tn * 4);
  float bv[4] = {bb.x, bb.y, bb.z, bb.w};
#pragma unroll
  for (int i = 0; i < 4; ++i) {
    float o[4];
#pragma unroll
    for (int j = 0; j < 4; ++j) {
      const float v = acc[i][j] + bv[j];
      o[j] = fmaxf(v, 0.f) + log1pf(__expf(-fabsf(v)));   // stable softplus
    }
    *(float4*)(dtb + (r0 + tm * 4 + i) * DM + n0 + tn * 4) = make_float4(o[0], o[1], o[2], o[3]);
  }
}

// ---------------------------------------------------------------------------
// Phase A: per-chunk local scan (h0=0) -> P (decay product), S (local state)
// thread = (b, chunk, d); 16 states in registers; B_in via wave-uniform loads
// ---------------------------------------------------------------------------
__global__ __launch_bounds__(256) void k3_scanA(const float* __restrict__ dtb,
                                                const float* __restrict__ x,
                                                const float* __restrict__ proj,
                                                const float* __restrict__ A_log,
                                                float* __restrict__ Pws,
                                                float* __restrict__ Sws) {
  const int tid = threadIdx.x;
  const int bid = blockIdx.x;
  const int dblk = bid & 3;
  const int c = (bid >> 2) & (NCHUNK - 1);
  const int b = bid >> 7;
  const int d = dblk * 256 + tid;
  float Aa[DS], h[DS], P[DS];
#pragma unroll
  for (int q = 0; q < 4; ++q) {
    float4 v = *(const float4*)(A_log + d * DS + q * 4);
    Aa[q * 4 + 0] = -__expf(v.x); Aa[q * 4 + 1] = -__expf(v.y);
    Aa[q * 4 + 2] = -__expf(v.z); Aa[q * 4 + 3] = -__expf(v.w);
  }
#pragma unroll
  for (int s = 0; s < DS; ++s) { h[s] = 0.f; P[s] = 1.f; }
  const int l0 = c * LC;
  for (int t = 0; t < LC; ++t) {
    const int row = b * LSEQ + l0 + t;
    const float dt = dtb[row * DM + d];
    const float xv = x[row * DM + d];
    const float u = dt * xv;
    float Bv[DS];
#pragma unroll
    for (int q = 0; q < 4; ++q)
      *(float4*)&Bv[q * 4] = *(const float4*)(proj + row * NP + DTR + q * 4);
#pragma unroll
    for (int s = 0; s < DS; ++s) {
      const float dA = __expf(dt * Aa[s]);
      P[s] *= dA;
      h[s] = fmaf(h[s], dA, u * Bv[s]);
    }
  }
  const int base = ((b * NCHUNK + c) * DM + d) * DS;
#pragma unroll
  for (int q = 0; q < 4; ++q) {
    *(float4*)(Pws + base + q * 4) = make_float4(P[q * 4], P[q * 4 + 1], P[q * 4 + 2], P[q * 4 + 3]);
    *(float4*)(Sws + base + q * 4) = make_float4(h[q * 4], h[q * 4 + 1], h[q * 4 + 2], h[q * 4 + 3]);
  }
}

// ---------------------------------------------------------------------------
// Phase B: sequential carry combine over chunks; thread = (b,d,s)
// ---------------------------------------------------------------------------
__global__ __launch_bounds__(256) void k3_comb(const float* __restrict__ Pws,
                                               const float* __restrict__ Sws,
                                               float* __restrict__ Hin) {
  const int t = blockIdx.x * 256 + threadIdx.x;
  const int b = t >> 14;
  const int dsi = t & 16383;
  float h = 0.f;
  for (int c = 0; c < NCHUNK; ++c) {
    const int idx = ((b * NCHUNK + c) << 14) + dsi;
    Hin[idx] = h;
    h = fmaf(Pws[idx], h, Sws[idx]);
  }
}

// ---------------------------------------------------------------------------
// Phase C: re-scan chunk from Hin carry, emit y = C.h + x*D in-place over dt
// ---------------------------------------------------------------------------
__global__ __launch_bounds__(256) void k3_scanC(float* __restrict__ io,
                                                const float* __restrict__ x,
                                                const float* __restrict__ proj,
                                                const float* __restrict__ A_log,
                                                const float* __restrict__ Dvec,
                                                const float* __restrict__ Hin) {
  const int tid = threadIdx.x;
  const int bid = blockIdx.x;
  const int dblk = bid & 3;
  const int c = (bid >> 2) & (NCHUNK - 1);
  const int b = bid >> 7;
  const int d = dblk * 256 + tid;
  float Aa[DS], h[DS];
#pragma unroll
  for (int q = 0; q < 4; ++q) {
    float4 v = *(const float4*)(A_log + d * DS + q * 4);
    Aa[q * 4 + 0] = -__expf(v.x); Aa[q * 4 + 1] = -__expf(v.y);
    Aa[q * 4 + 2] = -__expf(v.z); Aa[q * 4 + 3] = -__expf(v.w);
  }
  const int base = ((b * NCHUNK + c) * DM + d) * DS;
#pragma unroll
  for (int q = 0; q < 4; ++q)
    *(float4*)&h[q * 4] = *(const float4*)(Hin + base + q * 4);
  const float Dv = Dvec[d];
  const int l0 = c * LC;
  for (int t = 0; t < LC; ++t) {
    const int row = b * LSEQ + l0 + t;
    const float dt = io[row * DM + d];
    const float xv = x[row * DM + d];
    const float u = dt * xv;
    float Bv[DS], Cv[DS];
#pragma unroll
    for (int q = 0; q < 4; ++q) {
      *(float4*)&Bv[q * 4] = *(const float4*)(proj + row * NP + DTR + q * 4);
      *(float4*)&Cv[q * 4] = *(const float4*)(proj + row * NP + DTR + DS + q * 4);
    }
    float y = 0.f;
#pragma unroll
    for (int s = 0; s < DS; ++s) {
      const float dA = __expf(dt * Aa[s]);
      h[s] = fmaf(h[s], dA, u * Bv[s]);
      y = fmaf(h[s], Cv[s], y);
    }
    io[row * DM + d] = fmaf(xv, Dv, y);
  }
}

// ---------------------------------------------------------------------------
// ws layout (floats): proj 786432 | P 2097152 | S 2097152 | Hin 2097152
// total 28,311,552 bytes
// ---------------------------------------------------------------------------
extern "C" void kernel_launch(void* const* d_in, const int* in_sizes, int n_in,
                              void* d_out, int out_size, void* d_ws, size_t ws_size,
                              hipStream_t stream) {
  const float* x     = (const float*)d_in[0];
  const float* A_log = (const float*)d_in[1];
  const float* Dvec  = (const float*)d_in[2];
  const float* Wx    = (const float*)d_in[3];
  const float* dt_W  = (const float*)d_in[4];
  const float* dt_b  = (const float*)d_in[5];
  float* out = (float*)d_out;
  float* ws  = (float*)d_ws;
  float* proj = ws;
  float* Pws  = ws + 786432;
  float* Sws  = ws + 786432 + 2097152;
  float* Hin  = ws + 786432 + 2 * 2097152;

  hipMemsetAsync(proj, 0, 786432 * sizeof(float), stream);
  k1_proj<<<dim3(NROWS / K1_BM, K1_KSPLIT), 256, 0, stream>>>(x, Wx, proj);
  k2_dt<<<dim3(NROWS / 64, DM / 64), 256, 0, stream>>>(proj, dt_W, dt_b, out);
  k3_scanA<<<BB * NCHUNK * (DM / 256), 256, 0, stream>>>(out, x, proj, A_log, Pws, Sws);
  k3_comb<<<(BB * DM * DS) / 256, 256, 0, stream>>>(Pws, Sws, Hin);
  k3_scanC<<<BB * NCHUNK * (DM / 256), 256, 0, stream>>>(out, x, proj, A_log, Dvec, Hin);
}

// Round 2
// 210.718 us; speedup vs baseline: 1.3912x; 1.3912x over previous
//
#include <hip/hip_runtime.h>
#include <math.h>

#define DM    1024
#define DS    16
#define BB    4
#define LSEQ  2048
#define LOG2E 1.44269504088896f
#define LN2   0.69314718055994f

typedef short bf16x8 __attribute__((ext_vector_type(8)));
typedef float f32x4  __attribute__((ext_vector_type(4)));

__device__ __forceinline__ unsigned short f2bf(float f) {
  unsigned u = __builtin_bit_cast(unsigned, f);
  u += 0x7FFFu + ((u >> 16) & 1u);          // RNE truncate to bf16
  return (unsigned short)(u >> 16);
}
__device__ __forceinline__ float bf2f(unsigned short h) {
  unsigned u = ((unsigned)h) << 16;
  return __builtin_bit_cast(float, u);
}

// ---------------------------------------------------------------------------
// K0: pack Wx (96x1024) and dt_W (1024x64) into hi/lo bf16 pairs (bf16x3 trick)
// ---------------------------------------------------------------------------
__global__ __launch_bounds__(256) void k0_pack(const float* __restrict__ Wx,
                                               const float* __restrict__ dtW,
                                               short* __restrict__ Wxh, short* __restrict__ Wxl,
                                               short* __restrict__ dtWh, short* __restrict__ dtWl) {
  const int i = (blockIdx.x * 256 + threadIdx.x) * 4;   // 163840 total elems
  const float* src; short *dh, *dl; int off;
  if (i < 98304) { src = Wx;  dh = Wxh;  dl = Wxl;  off = i; }
  else           { src = dtW; dh = dtWh; dl = dtWl; off = i - 98304; }
  float4 v = *(const float4*)(src + off);
  float a[4] = {v.x, v.y, v.z, v.w};
  short h4[4], l4[4];
#pragma unroll
  for (int j = 0; j < 4; ++j) {
    unsigned short h = f2bf(a[j]);
    h4[j] = (short)h;
    l4[j] = (short)f2bf(a[j] - bf2f(h));
  }
  *(short4*)(dh + off) = make_short4(h4[0], h4[1], h4[2], h4[3]);
  *(short4*)(dl + off) = make_short4(l4[0], l4[1], l4[2], l4[3]);
}

// ---------------------------------------------------------------------------
// K1: proj = x(8192x1024) @ Wx^T(1024x96) via bf16x3 MFMA. Split-K over the
// block's 4 waves + LDS reduce (no atomics). Epilogue: cols 0..63 -> dt_r
// hi/lo bf16 (feeds k2); cols 64..95 -> BC fp32 (8192x32, feeds scans).
// Fragment layouts (m89-verified): A[m=lane&15][k=(lane>>4)*8+j],
//     B[k=(lane>>4)*8+j][n=lane&15], C/D: col=lane&15, row=(lane>>4)*4+i.
// ---------------------------------------------------------------------------
__global__ __launch_bounds__(256) void k1_proj_mfma(const float* __restrict__ x,
                                                    const short* __restrict__ Wxh,
                                                    const short* __restrict__ Wxl,
                                                    short* __restrict__ dtrh,
                                                    short* __restrict__ dtrl,
                                                    float* __restrict__ BC) {
  __shared__ float red[4][1536];
  const int tid = threadIdx.x, w = tid >> 6, lane = tid & 63;
  const int r0 = blockIdx.x * 16;
  const int m = lane & 15, kj = (lane >> 4) * 8;
  f32x4 acc[6];
#pragma unroll
  for (int nt = 0; nt < 6; ++nt) acc[nt] = (f32x4){0.f, 0.f, 0.f, 0.f};
  const int kb = w * 256;                                // split-K: 256 per wave
  for (int ks = 0; ks < 8; ++ks) {
    const int k = kb + ks * 32 + kj;
    const float* xp = x + (r0 + m) * DM + k;
    float4 a0 = *(const float4*)xp;
    float4 a1 = *(const float4*)(xp + 4);
    float av[8] = {a0.x, a0.y, a0.z, a0.w, a1.x, a1.y, a1.z, a1.w};
    bf16x8 ah, al;
#pragma unroll
    for (int j = 0; j < 8; ++j) {
      unsigned short h = f2bf(av[j]);
      ah[j] = (short)h;
      al[j] = (short)f2bf(av[j] - bf2f(h));
    }
#pragma unroll
    for (int nt = 0; nt < 6; ++nt) {
      const int bo = (nt * 16 + m) * DM + k;
      bf16x8 bh = *(const bf16x8*)(Wxh + bo);
      bf16x8 bl = *(const bf16x8*)(Wxl + bo);
      acc[nt] = __builtin_amdgcn_mfma_f32_16x16x32_bf16(ah, bh, acc[nt], 0, 0, 0);
      acc[nt] = __builtin_amdgcn_mfma_f32_16x16x32_bf16(ah, bl, acc[nt], 0, 0, 0);
      acc[nt] = __builtin_amdgcn_mfma_f32_16x16x32_bf16(al, bh, acc[nt], 0, 0, 0);
    }
  }
#pragma unroll
  for (int nt = 0; nt < 6; ++nt)
    *(f32x4*)&red[w][nt * 256 + lane * 4] = acc[nt];
  __syncthreads();
  const int p = tid;
  const int row = (p >> 6) * 4 + (p & 3), col16 = (p >> 2) & 15;
  const int grow = r0 + row;
#pragma unroll
  for (int nt = 0; nt < 6; ++nt) {
    const float v = red[0][nt * 256 + p] + red[1][nt * 256 + p] +
                    red[2][nt * 256 + p] + red[3][nt * 256 + p];
    if (nt < 4) {
      const int idx = grow * 64 + nt * 16 + col16;
      unsigned short h = f2bf(v);
      dtrh[idx] = (short)h;
      dtrl[idx] = (short)f2bf(v - bf2f(h));
    } else {
      BC[grow * 32 + (nt - 4) * 16 + col16] = v;
    }
  }
}

// ---------------------------------------------------------------------------
// K2: dt = softplus(dt_r(8192x64) @ dt_W^T(64x1024) + b) via bf16x3 MFMA,
//     written to d_out (overwritten in place by y in phase C).
// ---------------------------------------------------------------------------
__global__ __launch_bounds__(256) void k2_dt_mfma(const short* __restrict__ dtrh,
                                                  const short* __restrict__ dtrl,
                                                  const short* __restrict__ dtWh,
                                                  const short* __restrict__ dtWl,
                                                  const float* __restrict__ dt_b,
                                                  float* __restrict__ out) {
  const int tid = threadIdx.x, w = tid >> 6, lane = tid & 63;
  const int r0 = blockIdx.x * 16;
  const int n0 = blockIdx.y * 256 + w * 64;
  const int m = lane & 15, quad = lane >> 4, kj = quad * 8;
  f32x4 acc[4];
#pragma unroll
  for (int nt = 0; nt < 4; ++nt) acc[nt] = (f32x4){0.f, 0.f, 0.f, 0.f};
#pragma unroll
  for (int ks = 0; ks < 2; ++ks) {
    const int k = ks * 32 + kj;
    bf16x8 ah = *(const bf16x8*)(dtrh + (r0 + m) * 64 + k);
    bf16x8 al = *(const bf16x8*)(dtrl + (r0 + m) * 64 + k);
#pragma unroll
    for (int nt = 0; nt < 4; ++nt) {
      const int bo = (n0 + nt * 16 + m) * 64 + k;
      bf16x8 bh = *(const bf16x8*)(dtWh + bo);
      bf16x8 bl = *(const bf16x8*)(dtWl + bo);
      acc[nt] = __builtin_amdgcn_mfma_f32_16x16x32_bf16(ah, bh, acc[nt], 0, 0, 0);
      acc[nt] = __builtin_amdgcn_mfma_f32_16x16x32_bf16(ah, bl, acc[nt], 0, 0, 0);
      acc[nt] = __builtin_amdgcn_mfma_f32_16x16x32_bf16(al, bh, acc[nt], 0, 0, 0);
    }
  }
#pragma unroll
  for (int nt = 0; nt < 4; ++nt) {
    const int col = n0 + nt * 16 + m;
    const float bias = dt_b[col];
#pragma unroll
    for (int i = 0; i < 4; ++i) {
      const float v = acc[nt][i] + bias;
      const float sp = fmaxf(v, 0.f) +
          LN2 * __builtin_amdgcn_logf(1.f + __builtin_amdgcn_exp2f(-LOG2E * fabsf(v)));
      out[(r0 + quad * 4 + i) * DM + col] = sp;
    }
  }
}

// ---------------------------------------------------------------------------
// Phase A: per-chunk local scan (h0=0) -> P (decay product), S (local state).
// 1-ahead software prefetch of (dt, x, B). exp folded to raw v_exp (exp2).
// ---------------------------------------------------------------------------
template <int NC>
__global__ __launch_bounds__(256) void k3_scanA(const float* __restrict__ dtb,
                                                const float* __restrict__ x,
                                                const float* __restrict__ BC,
                                                const float* __restrict__ A_log,
                                                float* __restrict__ Pws,
                                                float* __restrict__ Sws) {
  constexpr int LC = LSEQ / NC;
  const int tid = threadIdx.x, bid = blockIdx.x;
  const int dblk = bid & 3, c = (bid >> 2) % NC, b = bid / (4 * NC);
  const int d = dblk * 256 + tid;
  float Aa[DS];
#pragma unroll
  for (int q = 0; q < 4; ++q) {
    float4 v = *(const float4*)(A_log + d * DS + q * 4);
    Aa[q * 4 + 0] = -__expf(v.x) * LOG2E; Aa[q * 4 + 1] = -__expf(v.y) * LOG2E;
    Aa[q * 4 + 2] = -__expf(v.z) * LOG2E; Aa[q * 4 + 3] = -__expf(v.w) * LOG2E;
  }
  float h[DS], Pp[DS];
#pragma unroll
  for (int s = 0; s < DS; ++s) { h[s] = 0.f; Pp[s] = 1.f; }
  const int rowb = b * LSEQ + c * LC;
  float dtc = dtb[rowb * DM + d], xc = x[rowb * DM + d];
  const float* bp0 = BC + rowb * 32;
  float4 b0 = *(const float4*)bp0, b1 = *(const float4*)(bp0 + 4),
         b2 = *(const float4*)(bp0 + 8), b3 = *(const float4*)(bp0 + 12);
  for (int t = 0; t < LC; ++t) {
    const int tn = (t + 1 < LC) ? t + 1 : t;
    const int rown = rowb + tn;
    const float dtn = dtb[rown * DM + d], xn = x[rown * DM + d];
    const float* bp = BC + rown * 32;
    const float4 n0 = *(const float4*)bp, n1 = *(const float4*)(bp + 4),
                 n2 = *(const float4*)(bp + 8), n3 = *(const float4*)(bp + 12);
    float Bv[DS];
    *(float4*)&Bv[0] = b0; *(float4*)&Bv[4] = b1;
    *(float4*)&Bv[8] = b2; *(float4*)&Bv[12] = b3;
    const float u = dtc * xc;
#pragma unroll
    for (int s = 0; s < DS; ++s) {
      const float dA = __builtin_amdgcn_exp2f(dtc * Aa[s]);
      Pp[s] *= dA;
      h[s] = fmaf(h[s], dA, u * Bv[s]);
    }
    dtc = dtn; xc = xn; b0 = n0; b1 = n1; b2 = n2; b3 = n3;
  }
  const int base = ((b * NC + c) * DM + d) * DS;
#pragma unroll
  for (int q = 0; q < 4; ++q) {
    *(float4*)(Pws + base + q * 4) = make_float4(Pp[q*4], Pp[q*4+1], Pp[q*4+2], Pp[q*4+3]);
    *(float4*)(Sws + base + q * 4) = make_float4(h[q*4], h[q*4+1], h[q*4+2], h[q*4+3]);
  }
}

// ---------------------------------------------------------------------------
// Phase B: carry combine; batch-8 prefetch breaks the load-latency chain.
// PH = Pws on input, overwritten with Hin (loads precede stores per batch).
// ---------------------------------------------------------------------------
template <int NC>
__global__ __launch_bounds__(256) void k3_comb(float* __restrict__ PH,
                                               const float* __restrict__ Sws) {
  const int t = blockIdx.x * 256 + threadIdx.x;
  const int b = t >> 14, dsi = t & 16383;
  const int cb0 = b * NC;
  float h = 0.f;
  for (int cb = 0; cb < NC; cb += 8) {
    float p[8], s[8];
#pragma unroll
    for (int j = 0; j < 8; ++j) {
      const int idx = ((cb0 + cb + j) << 14) + dsi;
      p[j] = PH[idx]; s[j] = Sws[idx];
    }
#pragma unroll
    for (int j = 0; j < 8; ++j) {
      const int idx = ((cb0 + cb + j) << 14) + dsi;
      PH[idx] = h;
      h = fmaf(p[j], h, s[j]);
    }
  }
}

// ---------------------------------------------------------------------------
// Phase C: re-scan chunk from Hin carry, y = C.h + x*D in place over dt.
// ---------------------------------------------------------------------------
template <int NC>
__global__ __launch_bounds__(256) void k3_scanC(float* __restrict__ io,
                                                const float* __restrict__ x,
                                                const float* __restrict__ BC,
                                                const float* __restrict__ A_log,
                                                const float* __restrict__ Dvec,
                                                const float* __restrict__ Hin) {
  constexpr int LC = LSEQ / NC;
  const int tid = threadIdx.x, bid = blockIdx.x;
  const int dblk = bid & 3, c = (bid >> 2) % NC, b = bid / (4 * NC);
  const int d = dblk * 256 + tid;
  float Aa[DS];
#pragma unroll
  for (int q = 0; q < 4; ++q) {
    float4 v = *(const float4*)(A_log + d * DS + q * 4);
    Aa[q * 4 + 0] = -__expf(v.x) * LOG2E; Aa[q * 4 + 1] = -__expf(v.y) * LOG2E;
    Aa[q * 4 + 2] = -__expf(v.z) * LOG2E; Aa[q * 4 + 3] = -__expf(v.w) * LOG2E;
  }
  float h[DS];
  const int base = ((b * NC + c) * DM + d) * DS;
#pragma unroll
  for (int q = 0; q < 4; ++q)
    *(float4*)&h[q * 4] = *(const float4*)(Hin + base + q * 4);
  const float Dv = Dvec[d];
  const int rowb = b * LSEQ + c * LC;
  float dtc = io[rowb * DM + d], xc = x[rowb * DM + d];
  const float* p0 = BC + rowb * 32;
  float4 b0 = *(const float4*)p0,      b1 = *(const float4*)(p0 + 4),
         b2 = *(const float4*)(p0 + 8), b3 = *(const float4*)(p0 + 12),
         c0 = *(const float4*)(p0 + 16), c1 = *(const float4*)(p0 + 20),
         c2 = *(const float4*)(p0 + 24), c3 = *(const float4*)(p0 + 28);
  for (int t = 0; t < LC; ++t) {
    const int tn = (t + 1 < LC) ? t + 1 : t;
    const int rown = rowb + tn;
    const float dtn = io[rown * DM + d], xn = x[rown * DM + d];
    const float* bp = BC + rown * 32;
    const float4 nb0 = *(const float4*)bp,        nb1 = *(const float4*)(bp + 4),
                 nb2 = *(const float4*)(bp + 8),  nb3 = *(const float4*)(bp + 12),
                 nc0 = *(const float4*)(bp + 16), nc1 = *(const float4*)(bp + 20),
                 nc2 = *(const float4*)(bp + 24), nc3 = *(const float4*)(bp + 28);
    float Bv[DS], Cv[DS];
    *(float4*)&Bv[0] = b0; *(float4*)&Bv[4] = b1;
    *(float4*)&Bv[8] = b2; *(float4*)&Bv[12] = b3;
    *(float4*)&Cv[0] = c0; *(float4*)&Cv[4] = c1;
    *(float4*)&Cv[8] = c2; *(float4*)&Cv[12] = c3;
    const float u = dtc * xc;
    float y = 0.f;
#pragma unroll
    for (int s = 0; s < DS; ++s) {
      const float dA = __builtin_amdgcn_exp2f(dtc * Aa[s]);
      h[s] = fmaf(h[s], dA, u * Bv[s]);
      y = fmaf(h[s], Cv[s], y);
    }
    io[(rowb + t) * DM + d] = fmaf(xc, Dv, y);
    dtc = dtn; xc = xn;
    b0 = nb0; b1 = nb1; b2 = nb2; b3 = nb3;
    c0 = nc0; c1 = nc1; c2 = nc2; c3 = nc3;
  }
}

// ---------------------------------------------------------------------------
// ws layout (shorts then floats):
//   Wxh/Wxl 98304 ea | dtWh/dtWl 65536 ea | dtrh/dtrl 524288 ea  (= 688128 floats)
//   BC 262144 f | P (NC*65536 f, becomes Hin) | S (NC*65536 f)
// NC=64 total: 37,355,520 B ; NC=32 total: 20,578,304 B
// ---------------------------------------------------------------------------
extern "C" void kernel_launch(void* const* d_in, const int* in_sizes, int n_in,
                              void* d_out, int out_size, void* d_ws, size_t ws_size,
                              hipStream_t stream) {
  const float* x     = (const float*)d_in[0];
  const float* A_log = (const float*)d_in[1];
  const float* Dvec  = (const float*)d_in[2];
  const float* Wx    = (const float*)d_in[3];
  const float* dt_W  = (const float*)d_in[4];
  const float* dt_b  = (const float*)d_in[5];
  float* out = (float*)d_out;
  float* ws  = (float*)d_ws;

  short* Wxh  = (short*)ws;
  short* Wxl  = Wxh + 98304;
  short* dtWh = Wxl + 98304;
  short* dtWl = dtWh + 65536;
  short* dtrh = dtWl + 65536;
  short* dtrl = dtrh + 524288;
  float* BC   = ws + 688128;
  float* P    = BC + 262144;           // re-used as Hin by k3_comb

  k0_pack<<<160, 256, 0, stream>>>(Wx, dt_W, Wxh, Wxl, dtWh, dtWl);
  k1_proj_mfma<<<512, 256, 0, stream>>>(x, Wxh, Wxl, dtrh, dtrl, BC);
  k2_dt_mfma<<<dim3(512, 4), 256, 0, stream>>>(dtrh, dtrl, dtWh, dtWl, dt_b, out);

  if (ws_size >= (size_t)(950272 + 2 * 64 * 65536) * 4) {
    constexpr int NC = 64;
    float* S = P + NC * 65536;
    k3_scanA<NC><<<BB * NC * 4, 256, 0, stream>>>(out, x, BC, A_log, P, S);
    k3_comb<NC><<<256, 256, 0, stream>>>(P, S);
    k3_scanC<NC><<<BB * NC * 4, 256, 0, stream>>>(out, x, BC, A_log, Dvec, P);
  } else {
    constexpr int NC = 32;
    float* S = P + NC * 65536;
    k3_scanA<NC><<<BB * NC * 4, 256, 0, stream>>>(out, x, BC, A_log, P, S);
    k3_comb<NC><<<256, 256, 0, stream>>>(P, S);
    k3_scanC<NC><<<BB * NC * 4, 256, 0, stream>>>(out, x, BC, A_log, Dvec, P);
  }
}